// Round 6
// baseline (414.156 us; speedup 1.0000x reference)
//
#include <hip/hip_runtime.h>
#include <math.h>

#define BB 8
#define NN 2048
#define FF 64
#define EPSV 1e-5f
#define EMB_SZ (BB * NN * FF)

// workspace float layout
#define WS_SQ      0                      // BB*NN
#define WS_ASUM    (BB * NN)              // BB*FF
#define WS_ASQ     (WS_ASUM + BB * FF)
#define WS_MEAN    (WS_ASQ + BB * FF)
#define WS_RSTD    (WS_MEAN + BB * FF)
#define WS_DEG     (WS_RSTD + BB * FF)    // BB*NN
#define WS_F32_END (WS_DEG + BB * NN)     // 34816 floats
// after WS_F32_END (16B aligned): embBf [BB*NN*FF] bf16, embnT [BB*FF*NN] bf16

typedef __attribute__((ext_vector_type(8))) short bf16x8;
typedef __attribute__((ext_vector_type(4))) float f32x4;
typedef unsigned short ushort_t;

#define P1 132   // trip-1 fp32 LDS row stride (floats): 528B rows, b128-aligned
#define P2 136   // trip-2 bf16 LDS row stride (elems): 272B rows, b128-aligned

__device__ inline ushort_t f2bf(float x) {
    union { float f; unsigned u; } v; v.f = x;
    return (ushort_t)((v.u + 0x7fffu + ((v.u >> 16) & 1u)) >> 16);
}

// ---------------------------------------------------------------------------
// Kernel 1: per-row squared norm (sq) + per-(b,f) partial sums for mean/var.
// emb_in pre-masked (rows >= nb zero) -> unmasked sums are exact.
// ---------------------------------------------------------------------------
__global__ __launch_bounds__(256) void k_stats(const float* __restrict__ emb,
                                               float* __restrict__ sq,
                                               float* __restrict__ asum,
                                               float* __restrict__ asq) {
    const int b    = blockIdx.y;
    const int lane = threadIdx.x & 63;
    const int grp  = threadIdx.x >> 6;
    const int base_i = blockIdx.x << 6;

    float s = 0.f, q = 0.f;
    for (int it = 0; it < 16; ++it) {
        const int i = base_i + (it << 2) + grp;
        const float x = emb[((size_t)(b * NN + i) << 6) + lane];
        const float x2 = x * x;
        s += x;
        q += x2;
        float r = x2;
        r += __shfl_xor(r, 1);
        r += __shfl_xor(r, 2);
        r += __shfl_xor(r, 4);
        r += __shfl_xor(r, 8);
        r += __shfl_xor(r, 16);
        r += __shfl_xor(r, 32);
        if (lane == 0) sq[b * NN + i] = r;
    }
    __shared__ float redS[4][64];
    __shared__ float redQ[4][64];
    redS[grp][lane] = s;
    redQ[grp][lane] = q;
    __syncthreads();
    if (threadIdx.x < 64) {
        const float ts = redS[0][lane] + redS[1][lane] + redS[2][lane] + redS[3][lane];
        const float tq = redQ[0][lane] + redQ[1][lane] + redQ[2][lane] + redQ[3][lane];
        atomicAdd(&asum[(b << 6) + lane], ts);
        atomicAdd(&asq[(b << 6) + lane], tq);
    }
}

// ---------------------------------------------------------------------------
// Kernel 2: finalize mean / rstd.  1 block, 512 threads (= B*F).
// ---------------------------------------------------------------------------
__global__ void k_finalize(const float* __restrict__ asum, const float* __restrict__ asq,
                           const int* __restrict__ nbp,
                           float* __restrict__ mean, float* __restrict__ rstd) {
    const int t = threadIdx.x;
    const int b = t >> 6;
    const float cnt = fmaxf((float)nbp[b], 1.f);
    const float m = asum[t] / cnt;
    float v = asq[t] / cnt - m * m;
    v = fmaxf(v, 0.f);
    mean[t] = m;
    rstd[t] = rsqrtf(v + EPSV);
}

// ---------------------------------------------------------------------------
// Kernel 3: one-shot bf16 operand precompute:
//   embBf[b][j][f] = bf16(emb)              (raw, row-major)
//   embnT[b][f][j] = bf16(emb_n) TRANSPOSED (normalized + masked)
// ---------------------------------------------------------------------------
__global__ __launch_bounds__(256) void k_prep(const float* __restrict__ emb,
                                              const float* __restrict__ meanp,
                                              const float* __restrict__ rstdp,
                                              const int* __restrict__ nbp,
                                              ushort_t* __restrict__ embBf,
                                              ushort_t* __restrict__ embnT) {
    __shared__ __align__(16) ushort_t T[64][72];
    const int b = blockIdx.y, j0 = blockIdx.x << 6;
    const int nb = nbp[b], bN = b * NN;
    const int t = threadIdx.x;
    const int j = t >> 2, fs = (t & 3) << 4;

    float mn[16], rs[16];
#pragma unroll
    for (int e = 0; e < 16; e += 4) {
        *(float4*)&mn[e] = *(const float4*)(meanp + (b << 6) + fs + e);
        *(float4*)&rs[e] = *(const float4*)(rstdp + (b << 6) + fs + e);
    }
    const float msk = (j0 + j < nb) ? 1.f : 0.f;
    const float* src = emb + ((size_t)(bN + j0 + j) << 6) + fs;
    __align__(16) float x[16];
    *(float4*)(x + 0)  = *(const float4*)(src + 0);
    *(float4*)(x + 4)  = *(const float4*)(src + 4);
    *(float4*)(x + 8)  = *(const float4*)(src + 8);
    *(float4*)(x + 12) = *(const float4*)(src + 12);
    __align__(16) ushort_t raw[16];
#pragma unroll
    for (int e = 0; e < 16; ++e) {
        raw[e] = f2bf(x[e]);
        T[fs + e][j] = f2bf((x[e] - mn[e]) * rs[e] * msk);
    }
    ushort_t* dst = embBf + ((size_t)(bN + j0 + j) << 6) + fs;
    *(bf16x8*)dst       = *(bf16x8*)&raw[0];
    *(bf16x8*)(dst + 8) = *(bf16x8*)&raw[8];
    __syncthreads();
    const int f = t >> 2, js = (t & 3) << 4;
    const bf16x8 v0 = *(bf16x8*)&T[f][js];
    const bf16x8 v1 = *(bf16x8*)&T[f][js + 8];
    ushort_t* dstT = embnT + ((size_t)(b * FF + f) << 11) + j0 + js;
    *(bf16x8*)dstT       = v0;
    *(bf16x8*)(dstT + 8) = v1;
}

// ---------------------------------------------------------------------------
// Kernel 4 (FUSED, barrier-free): adj + deg + op_adj partials.
// Grid (8 jchunks x 32 i-tiles x B) = 2048 blocks, 4 waves.  Wave w owns rows
// ib = i0 + w*16; per 128-j tile:
//   Gram MFMA (frags from global embBf)            [L2-hot]
//   acc -> wave-private LDS (C layout) -> read back row-major
//   vectorized epilogue: float4 adj_in / sq / store, exp, deg rowsum
//   final adj -> wave-private LDS as bf16 -> PV A-frags (row=l15, k=lq*8)
//   PV MFMA vs embnT (global, L2-hot) -> accP; one atomicAdd pass per block.
// All LDS is wave-private: NO __syncthreads anywhere (DS pipe in-order/wave).
// ---------------------------------------------------------------------------
__global__ __launch_bounds__(256, 3) void k_adj_fused(const ushort_t* __restrict__ embBf,
                                                      const ushort_t* __restrict__ embnT,
                                                      const float* __restrict__ adj_in,
                                                      const float* __restrict__ sq,
                                                      const float* __restrict__ sigp,
                                                      const float* __restrict__ cw,
                                                      const int* __restrict__ nbp,
                                                      float* __restrict__ adj_out,
                                                      float* __restrict__ deg,
                                                      float* __restrict__ opadj) {
    __shared__ __align__(16) float    ldsF[4][16 * P1];   // 33792 B
    __shared__ __align__(16) ushort_t ldsH[4][16 * P2];   // 17408 B

    const int b = blockIdx.z, i0 = blockIdx.y << 6, jbeg = blockIdx.x << 8;
    const int nb = nbp[b], bN = b * NN;
    const int tid = threadIdx.x, w = tid >> 6, lane = tid & 63;
    const int l15 = lane & 15, lq = lane >> 4;
    const int ib = i0 + w * 16;
    const int rrow = lane >> 2;         // row-major lane row (0..15)
    const int rcol = (lane & 3) << 5;   // row-major lane col base (0,32,64,96)

    float*    ldsf = ldsF[w];
    ushort_t* ldsh = ldsH[w];

    const float inv_sigma = 1.f / sigp[0];
    const float w0 = cw[0], w1 = cw[1];
    const bool ilive = (i0 < nb);

    bf16x8 a0 = {}, a1 = {};
    float sqi_r = 0.f, mi_r = 0.f;
    if (ilive) {
        const ushort_t* ap = embBf + ((size_t)(bN + ib + l15) << 6) + lq * 8;
        a0 = *(const bf16x8*)ap;
        a1 = *(const bf16x8*)(ap + 32);
        sqi_r = sq[bN + ib + rrow];
        mi_r = (ib + rrow < nb) ? 1.f : 0.f;
    }

    f32x4 accP[4];
#pragma unroll
    for (int c = 0; c < 4; ++c) accP[c] = (f32x4){0.f, 0.f, 0.f, 0.f};

    for (int t = 0; t < 2; ++t) {
        const int j0 = jbeg + (t << 7);
        float* orow = adj_out + ((size_t)(bN + ib + rrow) << 11) + j0 + rcol;

        if (!ilive || j0 >= nb) {
            const float4 z = make_float4(0.f, 0.f, 0.f, 0.f);
#pragma unroll
            for (int e = 0; e < 8; ++e) *(float4*)(orow + (e << 2)) = z;
            continue;
        }

        // ---- prefetch adj_in + sqj (row-major float4 lane layout)
        float4 ain[8], sqj4[8];
        const float* arow_in = adj_in + ((size_t)(bN + ib + rrow) << 11) + j0 + rcol;
#pragma unroll
        for (int e = 0; e < 8; ++e) ain[e] = *(const float4*)(arow_in + (e << 2));
#pragma unroll
        for (int e = 0; e < 8; ++e) sqj4[e] = *(const float4*)(sq + bN + j0 + rcol + (e << 2));

        // ---- Gram MFMA (fragments from global bf16)
        f32x4 acc[8];
#pragma unroll
        for (int c = 0; c < 8; ++c) acc[c] = (f32x4){0.f, 0.f, 0.f, 0.f};
#pragma unroll
        for (int c = 0; c < 8; ++c) {
            const ushort_t* bp = embBf + ((size_t)(bN + j0 + c * 16 + l15) << 6) + lq * 8;
            const bf16x8 b0 = *(const bf16x8*)bp;
            const bf16x8 b1 = *(const bf16x8*)(bp + 32);
            acc[c] = __builtin_amdgcn_mfma_f32_16x16x32_bf16(a0, b0, acc[c], 0, 0, 0);
            acc[c] = __builtin_amdgcn_mfma_f32_16x16x32_bf16(a1, b1, acc[c], 0, 0, 0);
        }

        // ---- trip 1: C-layout write (2-way aliasing, free)
#pragma unroll
        for (int c = 0; c < 8; ++c)
#pragma unroll
            for (int r = 0; r < 4; ++r)
                ldsf[(lq * 4 + r) * P1 + c * 16 + l15] = acc[c][r];

        // ---- trip 1 read (row-major) + vectorized epilogue
        float rsum = 0.f;
        float4 aout[8];
#pragma unroll
        for (int e = 0; e < 8; ++e) {
            const float4 dot = *(const float4*)&ldsf[rrow * P1 + rcol + (e << 2)];
            const int gj = j0 + rcol + (e << 2);
            float4 o;
            {
                float d2 = fmaxf(sqi_r + sqj4[e].x - 2.f * dot.x, 0.f);
                o.x = (w0 * ain[e].x + w1 * __expf(-d2 * inv_sigma)) * ((gj + 0 < nb) ? mi_r : 0.f);
                d2 = fmaxf(sqi_r + sqj4[e].y - 2.f * dot.y, 0.f);
                o.y = (w0 * ain[e].y + w1 * __expf(-d2 * inv_sigma)) * ((gj + 1 < nb) ? mi_r : 0.f);
                d2 = fmaxf(sqi_r + sqj4[e].z - 2.f * dot.z, 0.f);
                o.z = (w0 * ain[e].z + w1 * __expf(-d2 * inv_sigma)) * ((gj + 2 < nb) ? mi_r : 0.f);
                d2 = fmaxf(sqi_r + sqj4[e].w - 2.f * dot.w, 0.f);
                o.w = (w0 * ain[e].w + w1 * __expf(-d2 * inv_sigma)) * ((gj + 3 < nb) ? mi_r : 0.f);
            }
            aout[e] = o;
            rsum += o.x + o.y + o.z + o.w;
            *(float4*)(orow + (e << 2)) = o;   // float4 adj store
        }

        // ---- deg: 4 lanes (same row) hold disjoint col ranges
        rsum += __shfl_xor(rsum, 1);
        rsum += __shfl_xor(rsum, 2);
        if ((lane & 3) == 0) atomicAdd(&deg[bN + ib + rrow], rsum);

        // ---- trip 2: final adj -> bf16 LDS (row-major)
#pragma unroll
        for (int e2 = 0; e2 < 4; ++e2) {
            __align__(16) ushort_t pk[8];
            const float4 u = aout[e2 * 2], v = aout[e2 * 2 + 1];
            pk[0] = f2bf(u.x); pk[1] = f2bf(u.y); pk[2] = f2bf(u.z); pk[3] = f2bf(u.w);
            pk[4] = f2bf(v.x); pk[5] = f2bf(v.y); pk[6] = f2bf(v.z); pk[7] = f2bf(v.w);
            *(bf16x8*)&ldsh[rrow * P2 + rcol + (e2 << 3)] = *(bf16x8*)pk;
        }

        // ---- PV MFMA: accP[c] += adj_tile(16x128) @ emb_n^T
#pragma unroll
        for (int ks = 0; ks < 4; ++ks) {
            const bf16x8 af = *(const bf16x8*)&ldsh[l15 * P2 + ks * 32 + lq * 8];
#pragma unroll
            for (int c = 0; c < 4; ++c) {
                const bf16x8 bv = *(const bf16x8*)(embnT + ((size_t)(b * FF + c * 16 + l15) << 11)
                                                   + j0 + ks * 32 + lq * 8);
                accP[c] = __builtin_amdgcn_mfma_f32_16x16x32_bf16(af, bv, accP[c], 0, 0, 0);
            }
        }
    }

    if (ilive) {
#pragma unroll
        for (int c = 0; c < 4; ++c)
#pragma unroll
            for (int r = 0; r < 4; ++r) {
                const int gi = ib + lq * 4 + r;
                atomicAdd(opadj + ((size_t)(bN + gi) << 6) + c * 16 + l15, accP[c][r]);
            }
    }
}

// ---------------------------------------------------------------------------
// Kernel 5: epilogue.  Reads op_adj (emb region of d_out) + deg, builds
// [op_deg | op_adj], conv matmul, nu matmul, relu; overwrites emb_out rows.
// ---------------------------------------------------------------------------
__global__ __launch_bounds__(256) void k_epilogue(const float* __restrict__ emb,
                                                  const float* __restrict__ meanp,
                                                  const float* __restrict__ rstdp,
                                                  const float* __restrict__ degp,
                                                  const int* __restrict__ nbp,
                                                  const float* __restrict__ convW,
                                                  const float* __restrict__ convB,
                                                  const float* __restrict__ nuW,
                                                  const float* __restrict__ nuB,
                                                  float* __restrict__ emb_out) {
    __shared__ __align__(16) float smem[13056];
    float* xs = smem;          // [64][132] [i][op_deg|op_adj]
    float* us = smem + 8704;   // [64][68] emb_upd
    float* es = smem;          // reuse: [64][68] emb_in rows

    const int b   = blockIdx.y;
    const int i0  = blockIdx.x << 6;
    const int tid = threadIdx.x;
    const int tx = tid & 15, ty = tid >> 4;
    const int nb = nbp[b];
    const int bN = b * NN;
    const int sj  = tid >> 2;
    const int scb = (tid & 3) << 4;

    {
        const float4 m4 = *(const float4*)(meanp + (b << 6) + (tx << 2));
        const float4 r4 = *(const float4*)(rstdp + (b << 6) + (tx << 2));
#pragma unroll
        for (int u = 0; u < 4; ++u) {
            const int il = (ty << 2) + u;
            const int gi = i0 + il;
            const float msk = (gi < nb) ? 1.f : 0.f;
            const float dg = degp[bN + gi];
            const float4 v = *(const float4*)(emb + ((size_t)(bN + gi) << 6) + (tx << 2));
            float4 en;
            en.x = (v.x - m4.x) * r4.x * msk;
            en.y = (v.y - m4.y) * r4.y * msk;
            en.z = (v.z - m4.z) * r4.z * msk;
            en.w = (v.w - m4.w) * r4.w * msk;
            float4 od;
            od.x = dg * en.x; od.y = dg * en.y; od.z = dg * en.z; od.w = dg * en.w;
            *(float4*)&xs[il * 132 + (tx << 2)] = od;
            const float4 oa = *(const float4*)(emb_out + ((size_t)(bN + gi) << 6) + (tx << 2));
            *(float4*)&xs[il * 132 + 64 + (tx << 2)] = oa;
        }
    }
    __syncthreads();

    {
        float u4[4][4];
#pragma unroll
        for (int r = 0; r < 4; ++r)
#pragma unroll
            for (int c = 0; c < 4; ++c) u4[r][c] = 0.f;
        for (int fis = 0; fis < 128; fis += 4) {
            const float4 w0v = *(const float4*)(convW + ((fis + 0) << 6) + (tx << 2));
            const float4 w1v = *(const float4*)(convW + ((fis + 1) << 6) + (tx << 2));
            const float4 w2v = *(const float4*)(convW + ((fis + 2) << 6) + (tx << 2));
            const float4 w3v = *(const float4*)(convW + ((fis + 3) << 6) + (tx << 2));
#pragma unroll
            for (int r = 0; r < 4; ++r) {
                const float4 x = *(const float4*)&xs[((ty << 2) + r) * 132 + fis];
                u4[r][0] += x.x * w0v.x + x.y * w1v.x + x.z * w2v.x + x.w * w3v.x;
                u4[r][1] += x.x * w0v.y + x.y * w1v.y + x.z * w2v.y + x.w * w3v.y;
                u4[r][2] += x.x * w0v.z + x.y * w1v.z + x.z * w2v.z + x.w * w3v.z;
                u4[r][3] += x.x * w0v.w + x.y * w1v.w + x.z * w2v.w + x.w * w3v.w;
            }
        }
        const float4 cb4 = *(const float4*)(convB + (tx << 2));
#pragma unroll
        for (int r = 0; r < 4; ++r) {
            float4 o;
            o.x = u4[r][0] + cb4.x; o.y = u4[r][1] + cb4.y;
            o.z = u4[r][2] + cb4.z; o.w = u4[r][3] + cb4.w;
            *(float4*)&us[((ty << 2) + r) * 68 + (tx << 2)] = o;
        }
    }
    __syncthreads();

    {
        const float* pe = emb + ((size_t)(bN + i0 + sj) << 6) + scb;
#pragma unroll
        for (int u = 0; u < 4; ++u)
            *(float4*)&es[sj * 68 + scb + (u << 2)] = *(const float4*)(pe + (u << 2));
    }
    __syncthreads();

    {
        float u4[4][4];
#pragma unroll
        for (int r = 0; r < 4; ++r)
#pragma unroll
            for (int c = 0; c < 4; ++c) u4[r][c] = 0.f;
        for (int fis = 0; fis < 64; fis += 4) {
            const float4 w0v = *(const float4*)(nuW + ((fis + 0) << 6) + (tx << 2));
            const float4 w1v = *(const float4*)(nuW + ((fis + 1) << 6) + (tx << 2));
            const float4 w2v = *(const float4*)(nuW + ((fis + 2) << 6) + (tx << 2));
            const float4 w3v = *(const float4*)(nuW + ((fis + 3) << 6) + (tx << 2));
#pragma unroll
            for (int r = 0; r < 4; ++r) {
                const float4 x = *(const float4*)&es[((ty << 2) + r) * 68 + fis];
                u4[r][0] += x.x * w0v.x + x.y * w1v.x + x.z * w2v.x + x.w * w3v.x;
                u4[r][1] += x.x * w0v.y + x.y * w1v.y + x.z * w2v.y + x.w * w3v.y;
                u4[r][2] += x.x * w0v.z + x.y * w1v.z + x.z * w2v.z + x.w * w3v.z;
                u4[r][3] += x.x * w0v.w + x.y * w1v.w + x.z * w2v.w + x.w * w3v.w;
            }
        }
        for (int fis = 0; fis < 64; fis += 4) {
            const float4 w0v = *(const float4*)(nuW + ((64 + fis + 0) << 6) + (tx << 2));
            const float4 w1v = *(const float4*)(nuW + ((64 + fis + 1) << 6) + (tx << 2));
            const float4 w2v = *(const float4*)(nuW + ((64 + fis + 2) << 6) + (tx << 2));
            const float4 w3v = *(const float4*)(nuW + ((64 + fis + 3) << 6) + (tx << 2));
#pragma unroll
            for (int r = 0; r < 4; ++r) {
                const float4 x = *(const float4*)&us[((ty << 2) + r) * 68 + fis];
                u4[r][0] += x.x * w0v.x + x.y * w1v.x + x.z * w2v.x + x.w * w3v.x;
                u4[r][1] += x.x * w0v.y + x.y * w1v.y + x.z * w2v.y + x.w * w3v.y;
                u4[r][2] += x.x * w0v.z + x.y * w1v.z + x.z * w2v.z + x.w * w3v.z;
                u4[r][3] += x.x * w0v.w + x.y * w1v.w + x.z * w2v.w + x.w * w3v.w;
            }
        }
        const float4 nb4 = *(const float4*)(nuB + (tx << 2));
#pragma unroll
        for (int r = 0; r < 4; ++r) {
            const int gi = i0 + (ty << 2) + r;
            float4 o;
            o.x = fmaxf(u4[r][0] + nb4.x, 0.f);
            o.y = fmaxf(u4[r][1] + nb4.y, 0.f);
            o.z = fmaxf(u4[r][2] + nb4.z, 0.f);
            o.w = fmaxf(u4[r][3] + nb4.w, 0.f);
            *(float4*)(emb_out + ((size_t)(bN + gi) << 6) + (tx << 2)) = o;
        }
    }
}

// ---------------------------------------------------------------------------
extern "C" void kernel_launch(void* const* d_in, const int* in_sizes, int n_in,
                              void* d_out, int out_size, void* d_ws, size_t ws_size,
                              hipStream_t stream) {
    (void)in_sizes; (void)n_in; (void)out_size; (void)ws_size;
    const float* emb_in   = (const float*)d_in[0];
    const float* adj_in   = (const float*)d_in[1];
    const int*   nbp      = (const int*)d_in[3];
    const float* sigp     = (const float*)d_in[4];
    const float* cw       = (const float*)d_in[5];
    const float* convW    = (const float*)d_in[6];
    const float* convB    = (const float*)d_in[7];
    const float* nuW      = (const float*)d_in[8];
    const float* nuB      = (const float*)d_in[9];

    float* emb_out = (float*)d_out;
    float* adj_out = (float*)d_out + EMB_SZ;

    float* ws   = (float*)d_ws;
    float* sq   = ws + WS_SQ;
    float* asum = ws + WS_ASUM;
    float* asq  = ws + WS_ASQ;
    float* mean = ws + WS_MEAN;
    float* rstd = ws + WS_RSTD;
    float* deg  = ws + WS_DEG;
    ushort_t* embBf = (ushort_t*)(ws + WS_F32_END);
    ushort_t* embnT = embBf + (size_t)BB * NN * FF;

    // zero accumulators (ws/d_out are poisoned before every launch)
    hipMemsetAsync(asum, 0, (WS_F32_END - WS_ASUM) * sizeof(float), stream);
    hipMemsetAsync(emb_out, 0, (size_t)EMB_SZ * sizeof(float), stream);

    k_stats<<<dim3(32, BB), 256, 0, stream>>>(emb_in, sq, asum, asq);
    k_finalize<<<1, BB * FF, 0, stream>>>(asum, asq, nbp, mean, rstd);
    k_prep<<<dim3(32, BB), 256, 0, stream>>>(emb_in, mean, rstd, nbp, embBf, embnT);
    k_adj_fused<<<dim3(NN / 256, NN / 64, BB), 256, 0, stream>>>(embBf, embnT, adj_in,
                                                                 sq, sigp, cw, nbp,
                                                                 adj_out, deg, emb_out);
    k_epilogue<<<dim3(32, BB), 256, 0, stream>>>(emb_in, mean, rstd, deg, nbp,
                                                 convW, convB, nuW, nuB, emb_out);
}